// Round 2
// baseline (684.436 us; speedup 1.0000x reference)
//
#include <hip/hip_runtime.h>
#include <cstdint>
#include <cmath>
#include <cstring>
#include <map>
#include <tuple>
#include <vector>

#define SIG_LEN 32768
#define N_KERNELS 2000
#define NJOBS (N_KERNELS * 2)
#define TILES 32
#define TILE_W 1024

struct JobP { int out_base; unsigned packed; };

// ---------------- host-side replication of np.random.RandomState(0) ----------
namespace nprng {
struct MT {
  uint32_t key[624]; int pos; bool has_gauss;
  void seed(uint32_t s) {
    for (int i = 0; i < 624; i++) { key[i] = s; s = 1812433253u * (s ^ (s >> 30)) + (uint32_t)i + 1u; }
    pos = 624; has_gauss = false;
  }
  void gen() {
    const uint32_t UM = 0x80000000u, LM = 0x7fffffffu, MA = 0x9908b0dfu;
    for (int i = 0; i < 624; i++) {
      uint32_t y = (key[i] & UM) | (key[(i + 1) % 624] & LM);
      key[i] = key[(i + 397) % 624] ^ (y >> 1) ^ ((y & 1u) ? MA : 0u);
    }
    pos = 0;
  }
  uint32_t next32() {
    if (pos == 624) gen();
    uint32_t y = key[pos++];
    y ^= y >> 11; y ^= (y << 7) & 0x9d2c5680u; y ^= (y << 15) & 0xefc60000u; y ^= y >> 18;
    return y;
  }
  double nextD() {
    uint32_t a = next32() >> 5, b = next32() >> 6;
    return ((double)a * 67108864.0 + (double)b) / 9007199254740992.0;
  }
  // numpy legacy randint (rk_interval-compatible): masked rejection over
  // SINGLE 32-bit draws when rng fits in 32 bits (stream-compat w/ numpy<=1.16).
  // Verified: seed(0) -> randint(0,10) == 5 via draws 2357136044,2546248239,3071714933.
  uint32_t bounded(uint32_t rng) {
    uint32_t mask = rng;
    mask |= mask >> 1; mask |= mask >> 2; mask |= mask >> 4;
    mask |= mask >> 8; mask |= mask >> 16;
    uint32_t v;
    do { v = next32() & mask; } while (v > rng);
    return v;
  }
  // numpy legacy_gauss (polar), values discarded — only stream position matters
  void consume_gauss(int n) {
    for (int i = 0; i < n; i++) {
      if (has_gauss) { has_gauss = false; continue; }
      double x1, x2, r2;
      do {
        x1 = 2.0 * nextD() - 1.0;
        x2 = 2.0 * nextD() - 1.0;
        r2 = x1 * x1 + x2 * x2;
      } while (r2 >= 1.0 || r2 == 0.0);
      has_gauss = true;
    }
  }
};
} // namespace nprng

static JobP g_jobs[NJOBS];

static void build_jobs() {
  nprng::MT mt; mt.seed(0);
  static const int KS[3] = {7, 9, 11};
  int K[N_KERNELS], D[N_KERNELS], P[N_KERNELS], E[N_KERNELS];
  for (int i = 0; i < N_KERNELS; i++) {
    int k = KS[(int)mt.bounded(2)];                       // rng.choice((7,9,11)) -> randint(0,3)
    int M = (int)std::log2((double)(SIG_LEN - 1) / (double)(k - 1)); // 12 / 11 / 11
    int e = (int)mt.bounded((uint32_t)(M - 1));           // rng.randint(0, M)
    int d = 1 << e;
    double r = mt.nextD();                                // rng.rand()
    int p = (r <= 0.5) ? 0 : ((k - 1) * d / 2);
    mt.nextD();                                           // rng.uniform(-1,1) for bias
    mt.consume_gauss(k);                                  // rng.normal(size=k)
    K[i] = k; D[i] = d; P[i] = p; E[i] = e;
  }
  std::map<std::tuple<int, int, int>, std::vector<int>> groups;
  for (int i = 0; i < N_KERNELS; i++)
    groups[std::make_tuple(K[i], D[i], P[i])].push_back(i);
  long long off = 0; int jn = 0;
  for (auto& kv : groups) {
    int k = std::get<0>(kv.first), d = std::get<1>(kv.first), p = std::get<2>(kv.first);
    int out_len = SIG_LEN + 2 * p - d * (k - 1);
    int ng = (int)kv.second.size();
    for (int c = 0; c < ng; c++) {
      int i = kv.second[c];
      int kcode = (k - 7) / 2;
      for (int n = 0; n < 2; n++) {
        g_jobs[jn].out_base = (int)(off + (long long)(n * ng + c) * out_len);
        g_jobs[jn].packed = (unsigned)i | ((unsigned)kcode << 11) | ((unsigned)E[i] << 13)
                          | ((unsigned)(p ? 1 : 0) << 17) | ((unsigned)n << 18);
        jn++;
      }
    }
    off += 2LL * ng * out_len;
  }
}

// ------------------------------- device side ---------------------------------
template <int K>
__device__ __forceinline__ void conv_run(const float* __restrict__ xs,
                                         const float* __restrict__ wrow, float bias,
                                         int d, int p, int out_len, int tbase,
                                         float* __restrict__ op) {
  float w[K];
#pragma unroll
  for (int q = 0; q < K; q++) w[q] = wrow[q];
  int tid = threadIdx.x;
  bool fast = (tbase + TILE_W <= out_len) && (tbase >= p) &&
              (tbase + (TILE_W - 1) + (K - 1) * d - p < SIG_LEN);
  if (fast) {
    const float* xp = xs + (tbase + tid - p);
    float a0 = bias, a1 = bias, a2 = bias, a3 = bias;
#pragma unroll
    for (int q = 0; q < K; q++) {
      a0 += w[q] * xp[0];
      a1 += w[q] * xp[256];
      a2 += w[q] * xp[512];
      a3 += w[q] * xp[768];
      xp += d;
    }
    float* o = op + tbase + tid;
    __builtin_nontemporal_store(a0, o);
    __builtin_nontemporal_store(a1, o + 256);
    __builtin_nontemporal_store(a2, o + 512);
    __builtin_nontemporal_store(a3, o + 768);
  } else {
#pragma unroll
    for (int s = 0; s < 4; s++) {
      int t = tbase + tid + s * 256;
      if (t < out_len) {
        float acc = bias;
#pragma unroll
        for (int q = 0; q < K; q++) {
          int idx = t + q * d - p;
          if ((unsigned)idx < (unsigned)SIG_LEN) acc += w[q] * xs[idx];
        }
        __builtin_nontemporal_store(acc, op + t);
      }
    }
  }
}

__global__ __launch_bounds__(256) void rocket_kernel(const float* __restrict__ x,
                                                     const float* __restrict__ W,
                                                     const float* __restrict__ B,
                                                     const JobP* __restrict__ jobs,
                                                     float* __restrict__ out) {
  int jb = blockIdx.x >> 5;            // / TILES
  int tile = blockIdx.x & (TILES - 1); // % TILES
  int out_base = __builtin_amdgcn_readfirstlane(jobs[jb].out_base);
  unsigned packed = (unsigned)__builtin_amdgcn_readfirstlane((int)jobs[jb].packed);
  int widx = packed & 2047;
  int kcode = (packed >> 11) & 3;
  int e = (packed >> 13) & 15;
  int pflag = (packed >> 17) & 1;
  int n = (packed >> 18) & 1;
  int k = 7 + 2 * kcode;
  int d = 1 << e;
  int p = pflag ? (((k - 1) * d) >> 1) : 0;
  int out_len = SIG_LEN + 2 * p - (k - 1) * d;
  int tbase = tile * TILE_W;
  if (tbase >= out_len) return;
  const float* xs = x + n * SIG_LEN;
  const float* wrow = W + widx * 11;
  float bias = B[widx];
  float* op = out + out_base;
  if (kcode == 0)      conv_run<7>(xs, wrow, bias, d, p, out_len, tbase, op);
  else if (kcode == 1) conv_run<9>(xs, wrow, bias, d, p, out_len, tbase, op);
  else                 conv_run<11>(xs, wrow, bias, d, p, out_len, tbase, op);
}

extern "C" void kernel_launch(void* const* d_in, const int* in_sizes, int n_in,
                              void* d_out, int out_size, void* d_ws, size_t ws_size,
                              hipStream_t stream) {
  // Deterministic host-side rebuild every call (no static guards; same work
  // each call). During graph replay the captured H2D memcpy node re-reads
  // g_jobs (static storage, rebuilt identically) — this also re-fills d_ws
  // after the harness re-poisons it.
  build_jobs();
  const float* x = (const float*)d_in[0];
  const float* W = (const float*)d_in[1];
  const float* B = (const float*)d_in[2];
  JobP* jdev = (JobP*)d_ws;
  hipMemcpyAsync(jdev, g_jobs, sizeof(g_jobs), hipMemcpyHostToDevice, stream);
  rocket_kernel<<<dim3(NJOBS * TILES), dim3(256), 0, stream>>>(x, W, B, jdev, (float*)d_out);
}